// Round 1
// baseline (364.450 us; speedup 1.0000x reference)
//
#include <hip/hip_runtime.h>

typedef unsigned int uint;

#define TD 20000
// ws layout in float units:
//  H:      [200][12][4]  = 9600 floats  (FIR taps: {e_s, i_s, e_ns, i_ns} per (k,s))
//  maskE:  2000 u32      (bit s set iff C_syn_e[s][e] != 0)
//  maskI:  500 u32
//  IN:     [20000][24]   (e in 0..11, i in 12..23)
//  SYN:    [20000][24]   (syn_s in 0..11, syn_ns in 12..23)
//  A:      [20000][12]   (sigmoid(X_ns) per step)
#define WS_H      0
#define WS_MASKE  9600
#define WS_MASKI  11600
#define WS_IN     12288
#define WS_SYN    492288
#define WS_A      972288

__device__ __forceinline__ float sigf(float x) { return 1.f / (1.f + __expf(-x)); }

// ---------------- K1: FIR kernels + connectivity bitmasks ----------------
__global__ __launch_bounds__(256) void k1_precomp(
    const float* __restrict__ Ce, const float* __restrict__ Ci,
    const float* __restrict__ Wsy_s, const float* __restrict__ Wsy_ns,
    const float* __restrict__ Del_s, const float* __restrict__ Del_ns,
    float* __restrict__ ws) {
  int p = blockIdx.x * 256 + threadIdx.x;
  if (p < 2400) {
    int k = p / 12, s = p - (p / 12) * 12;
    float o[4];
    for (int ch = 0; ch < 2; ++ch) {
      const float* W = ch ? Wsy_ns : Wsy_s;
      const float* D = ch ? Del_ns : Del_s;
      for (int c = 0; c < 2; ++c) {
        float ts = fmaxf((float)k - __expf(D[s * 2 + c]), 0.f);
        float v = 0.f;
        for (int b = 0; b < 3; ++b) {
          float tt = ts * __expf(-0.5f * (float)b);
          v += W[s * 6 + b * 2 + c] * tt * __expf(-tt);
        }
        o[ch * 2 + c] = v;
      }
    }
    float* H = ws + WS_H + (size_t)(k * 12 + s) * 4;
    H[0] = o[0]; H[1] = o[1]; H[2] = o[2]; H[3] = o[3];
  }
  int q = p - 2400;
  if (q >= 0 && q < 2500) {
    uint m = 0;
    if (q < 2000) {
      for (int s = 0; s < 12; ++s) m |= (Ce[s * 2000 + q] != 0.f ? (1u << s) : 0u);
    } else {
      int e = q - 2000;
      for (int s = 0; s < 12; ++s) m |= (Ci[s * 500 + e] != 0.f ? (1u << s) : 0u);
    }
    ((uint*)(ws + WS_MASKE))[q] = m;
  }
}

// ---------------- K2: IN = S @ C^T as binary popcount matmul ----------------
// wave-per-row; C as 12-bit masks in LDS; integer-exact.
__global__ __launch_bounds__(256) void k2_project(
    const float* __restrict__ Se, const float* __restrict__ Si,
    float* __restrict__ ws) {
  __shared__ __align__(16) uint mE[2000];
  __shared__ __align__(16) uint mI[500];
  {
    const uint* g = (const uint*)(ws + WS_MASKE);
    for (int p = threadIdx.x; p < 2500; p += 256) {
      if (p < 2000) mE[p] = g[p];
      else mI[p - 2000] = g[p];
    }
  }
  __syncthreads();
  const int lane = threadIdx.x & 63;
  const int wv = blockIdx.x * 4 + (threadIdx.x >> 6);  // 2048 waves
  const int t0 = wv * 10;
  float* INb = ws + WS_IN;
  const uint4* ME4 = (const uint4*)mE;
  const uint4* MI4 = (const uint4*)mI;
  for (int t = t0; t < t0 + 10; ++t) {
    if (t >= TD) break;
    uint acc[12];
#pragma unroll
    for (int s = 0; s < 12; ++s) acc[s] = 0u;
    const float4* Sr = (const float4*)(Se + (size_t)t * 2000);
#pragma unroll
    for (int it = 0; it < 8; ++it) {
      int i4 = lane + it * 64;
      if (i4 < 500) {
        float4 sv = Sr[i4];
        uint4 mv = ME4[i4];
        uint m0 = (sv.x != 0.f) ? mv.x : 0u;
        uint m1 = (sv.y != 0.f) ? mv.y : 0u;
        uint m2 = (sv.z != 0.f) ? mv.z : 0u;
        uint m3 = (sv.w != 0.f) ? mv.w : 0u;
#pragma unroll
        for (int s = 0; s < 12; ++s)
          acc[s] += ((m0 >> s) & 1u) + ((m1 >> s) & 1u) + ((m2 >> s) & 1u) + ((m3 >> s) & 1u);
      }
    }
    const float4* Sir = (const float4*)(Si + (size_t)t * 500);
#pragma unroll
    for (int it = 0; it < 2; ++it) {
      int i4 = lane + it * 64;
      if (i4 < 125) {
        float4 sv = Sir[i4];
        uint4 mv = MI4[i4];
        uint m0 = (sv.x != 0.f) ? mv.x : 0u;
        uint m1 = (sv.y != 0.f) ? mv.y : 0u;
        uint m2 = (sv.z != 0.f) ? mv.z : 0u;
        uint m3 = (sv.w != 0.f) ? mv.w : 0u;
#pragma unroll
        for (int s = 0; s < 12; ++s)
          acc[s] += ((((m0 >> s) & 1u) + ((m1 >> s) & 1u) + ((m2 >> s) & 1u) + ((m3 >> s) & 1u)) << 16);
      }
    }
#pragma unroll
    for (int s = 0; s < 12; ++s) {
      uint v = acc[s];
      v += __shfl_xor(v, 32, 64);
      v += __shfl_xor(v, 16, 64);
      v += __shfl_xor(v, 8, 64);
      v += __shfl_xor(v, 4, 64);
      v += __shfl_xor(v, 2, 64);
      v += __shfl_xor(v, 1, 64);
      acc[s] = v;
    }
    if (lane == 0) {
      float4* o = (float4*)(INb + (size_t)t * 24);
      o[0] = make_float4((float)(acc[0] & 0xffffu), (float)(acc[1] & 0xffffu),
                         (float)(acc[2] & 0xffffu), (float)(acc[3] & 0xffffu));
      o[1] = make_float4((float)(acc[4] & 0xffffu), (float)(acc[5] & 0xffffu),
                         (float)(acc[6] & 0xffffu), (float)(acc[7] & 0xffffu));
      o[2] = make_float4((float)(acc[8] & 0xffffu), (float)(acc[9] & 0xffffu),
                         (float)(acc[10] & 0xffffu), (float)(acc[11] & 0xffffu));
      o[3] = make_float4((float)(acc[0] >> 16), (float)(acc[1] >> 16),
                         (float)(acc[2] >> 16), (float)(acc[3] >> 16));
      o[4] = make_float4((float)(acc[4] >> 16), (float)(acc[5] >> 16),
                         (float)(acc[6] >> 16), (float)(acc[7] >> 16));
      o[5] = make_float4((float)(acc[8] >> 16), (float)(acc[9] >> 16),
                         (float)(acc[10] >> 16), (float)(acc[11] >> 16));
    }
  }
}

// ---------------- K3: causal FIR, K=200 ----------------
// block = 64 output t's; 4 waves split k-range; channel-major LDS tile (stride-1
// across lanes => conflict-free); H taps are wave-uniform => scalar loads.
__global__ __launch_bounds__(256) void k3_conv(float* __restrict__ ws) {
  __shared__ float tile[24 * 263];
  __shared__ float red[4 * 64 * 24];
  const float* INb = ws + WS_IN;
  const float4* H4 = (const float4*)(ws + WS_H);
  const int t0 = blockIdx.x * 64;
  for (int p = threadIdx.x; p < 24 * 263; p += 256) {
    int row = p / 24, ch = p - row * 24;
    int g = t0 - 199 + row;
    tile[ch * 263 + row] = (g >= 0 && g < TD) ? INb[(size_t)g * 24 + ch] : 0.f;
  }
  __syncthreads();
  const int lane = threadIdx.x & 63;
  const int q = threadIdx.x >> 6;
  float accs[12], accn[12];
#pragma unroll
  for (int s = 0; s < 12; ++s) { accs[s] = 0.f; accn[s] = 0.f; }
  for (int kk = 0; kk < 25; ++kk) {
    int k = q * 50 + kk * 2;        // this pair covers taps k and k+1
    int rb = lane + 199 - k - 1;    // LDS row of tap k+1 (tap k is rb+1)
#pragma unroll
    for (int s = 0; s < 12; ++s) {
      float ve0 = tile[s * 263 + rb];
      float ve1 = tile[s * 263 + rb + 1];
      float vi0 = tile[(12 + s) * 263 + rb];
      float vi1 = tile[(12 + s) * 263 + rb + 1];
      float4 h0 = H4[k * 12 + s];
      float4 h1 = H4[(k + 1) * 12 + s];
      accs[s] += h0.x * ve1 + h0.y * vi1 + h1.x * ve0 + h1.y * vi0;
      accn[s] += h0.z * ve1 + h0.w * vi1 + h1.z * ve0 + h1.w * vi0;
    }
  }
  float* myred = red + (q * 64 + lane) * 24;
#pragma unroll
  for (int s = 0; s < 12; ++s) { myred[s] = accs[s]; myred[12 + s] = accn[s]; }
  __syncthreads();
  for (int p = threadIdx.x; p < 64 * 24; p += 256) {
    int row = p / 24;
    if (t0 + row < TD) {
      float sum = red[p] + red[1536 + p] + red[3072 + p] + red[4608 + p];
      ws[WS_SYN + (size_t)t0 * 24 + p] = sum;
    }
  }
}

// ---------------- K4: ns-chain. C_den strictly lower-tri => nilpotent =>
// exact 11-step influence horizon; chunk time, warm up 11 steps. ----------------
__global__ __launch_bounds__(64) void k4_chain(
    const float* __restrict__ Cden, const float* __restrict__ Wns_sub,
    const float* __restrict__ Th_ns, float* __restrict__ ws) {
  int c = blockIdx.x * 64 + threadIdx.x;
  if (c >= 2500) return;
  int t0 = c * 8;
  int start = t0 - 11; if (start < 0) start = 0;
  int end = t0 + 8; if (end > TD) end = TD;
  float dns[12][12];
#pragma unroll
  for (int i = 1; i < 12; ++i)
#pragma unroll
    for (int j = 0; j < i; ++j) dns[i][j] = Cden[i * 12 + j] * Wns_sub[j];
  float th[12];
#pragma unroll
  for (int i = 0; i < 12; ++i) th[i] = Th_ns[i];
  float ap[12];
#pragma unroll
  for (int i = 0; i < 12; ++i) ap[i] = 0.f;
  const float* SYN = ws + WS_SYN;
  float* A = ws + WS_A;
  for (int t = start; t < end; ++t) {
    const float4* sr = (const float4*)(SYN + (size_t)t * 24 + 12);
    float4 s0 = sr[0], s1 = sr[1], s2 = sr[2];
    float sn[12] = {s0.x, s0.y, s0.z, s0.w, s1.x, s1.y, s1.z, s1.w,
                    s2.x, s2.y, s2.z, s2.w};
    float an[12];
#pragma unroll
    for (int i = 0; i < 12; ++i) {
      float x = sn[i] + th[i];
#pragma unroll
      for (int j = 0; j < i; ++j) x += dns[i][j] * ap[j];
      an[i] = sigf(x);
    }
#pragma unroll
    for (int i = 0; i < 12; ++i) ap[i] = an[i];
    if (t >= t0) {
      float4* o = (float4*)(A + (size_t)t * 12);
      o[0] = make_float4(an[0], an[1], an[2], an[3]);
      o[1] = make_float4(an[4], an[5], an[6], an[7]);
      o[2] = make_float4(an[8], an[9], an[10], an[11]);
    }
  }
}

// ---------------- K5: epilogue, fully parallel over t ----------------
// s-chain has no recurrence: carry uses closed-form B[t-1][0] and A[t-1].
__global__ __launch_bounds__(256) void k5_out(
    const float* __restrict__ Cden, const float* __restrict__ Ws_sub,
    const float* __restrict__ Wns_sub, const float* __restrict__ Th_s,
    const float* __restrict__ ws, float* __restrict__ out) {
  __shared__ float lout[256 * 35];
  const int t = blockIdx.x * 256 + threadIdx.x;
  float v[35];
#pragma unroll
  for (int m = 0; m < 35; ++m) v[m] = 0.f;
  if (t < TD) {
    const float* SYN = ws + WS_SYN;
    const float* A = ws + WS_A;
    float at[12];
    {
      const float4* ar = (const float4*)(A + (size_t)t * 12);
      float4 a0 = ar[0], a1 = ar[1], a2 = ar[2];
      at[0] = a0.x; at[1] = a0.y; at[2] = a0.z; at[3] = a0.w;
      at[4] = a1.x; at[5] = a1.y; at[6] = a1.z; at[7] = a1.w;
      at[8] = a2.x; at[9] = a2.y; at[10] = a2.z; at[11] = a2.w;
    }
    float sn[12];
    {
      const float4* sr = (const float4*)(SYN + (size_t)t * 24);
      float4 s0 = sr[0], s1 = sr[1], s2 = sr[2];
      sn[0] = s0.x; sn[1] = s0.y; sn[2] = s0.z; sn[3] = s0.w;
      sn[4] = s1.x; sn[5] = s1.y; sn[6] = s1.z; sn[7] = s1.w;
      sn[8] = s2.x; sn[9] = s2.y; sn[10] = s2.z; sn[11] = s2.w;
    }
    float carry[12];
    if (t == 0) {
#pragma unroll
      for (int j = 0; j < 12; ++j) carry[j] = 0.f;
    } else {
      carry[0] = Ws_sub[0] * sigf(SYN[(size_t)(t - 1) * 24] + Th_s[0]);
      const float4* ar = (const float4*)(A + (size_t)(t - 1) * 12);
      float4 a0 = ar[0], a1 = ar[1], a2 = ar[2];
      float ap[12] = {a0.x, a0.y, a0.z, a0.w, a1.x, a1.y, a1.z, a1.w,
                      a2.x, a2.y, a2.z, a2.w};
#pragma unroll
      for (int j = 1; j < 12; ++j) carry[j] = Ws_sub[j] * ap[j];
    }
    float B[12];
#pragma unroll
    for (int i = 0; i < 12; ++i) {
      float x = sn[i] + Th_s[i];
#pragma unroll
      for (int j = 0; j < i; ++j) x += Cden[i * 12 + j] * carry[j];
      B[i] = sigf(x);
    }
    v[0] = B[0] * Ws_sub[0];
#pragma unroll
    for (int i = 1; i < 12; ++i) v[i] = at[i] * Ws_sub[i];
#pragma unroll
    for (int i = 0; i < 12; ++i) v[12 + i] = at[i] * Wns_sub[i];
#pragma unroll
    for (int i = 1; i < 12; ++i) v[23 + i] = B[i];
  }
#pragma unroll
  for (int m = 0; m < 35; ++m) lout[threadIdx.x * 35 + m] = v[m];
  __syncthreads();
  const int t0 = blockIdx.x * 256;
  int nrow = TD - t0; if (nrow > 256) nrow = 256;
  const int valid = nrow * 35;
  for (int p = threadIdx.x; p < valid; p += 256) out[(size_t)t0 * 35 + p] = lout[p];
}

extern "C" void kernel_launch(void* const* d_in, const int* in_sizes, int n_in,
                              void* d_out, int out_size, void* d_ws, size_t ws_size,
                              hipStream_t stream) {
  const float* Se = (const float*)d_in[0];
  const float* Si = (const float*)d_in[1];
  const float* Ce = (const float*)d_in[2];
  const float* Ci = (const float*)d_in[3];
  const float* Cden = (const float*)d_in[4];
  const float* Wsy_s = (const float*)d_in[5];
  const float* Wsy_ns = (const float*)d_in[6];
  const float* Del_s = (const float*)d_in[7];
  const float* Del_ns = (const float*)d_in[8];
  const float* Th_s = (const float*)d_in[9];
  const float* Th_ns = (const float*)d_in[10];
  const float* Ws_sub = (const float*)d_in[11];
  const float* Wns_sub = (const float*)d_in[12];
  // d_in[13..16] (hist/prop weights) multiply an identically-zero history buffer.
  float* ws = (float*)d_ws;
  float* out = (float*)d_out;

  k1_precomp<<<20, 256, 0, stream>>>(Ce, Ci, Wsy_s, Wsy_ns, Del_s, Del_ns, ws);
  k2_project<<<512, 256, 0, stream>>>(Se, Si, ws);
  k3_conv<<<313, 256, 0, stream>>>(ws);
  k4_chain<<<40, 64, 0, stream>>>(Cden, Wns_sub, Th_ns, ws);
  k5_out<<<79, 256, 0, stream>>>(Cden, Ws_sub, Wns_sub, Th_s, ws, out);
}

// Round 2
// 333.010 us; speedup vs baseline: 1.0944x; 1.0944x over previous
//
#include <hip/hip_runtime.h>

typedef unsigned int uint;
typedef unsigned long long u64;

#define TD 20000
// ws layout in float units:
//  H:      [200][12][4]  = 9600 floats  (FIR taps: {e_s, i_s, e_ns, i_ns} per (k,s))
//  SPREAD: 2500 uint2    (5-bit-field spread masks: bit s of connectivity -> bit 5s)
//          entries 0..1999 = E neurons, 2000..2499 = I neurons
//  IN:     [20000][24]   (e counts in 0..11, i counts in 12..23)
//  SYN:    [20000][24]   (syn_s in 0..11, syn_ns in 12..23)
#define WS_H      0
#define WS_SPREAD 9600
#define WS_IN     14600
#define WS_SYN    494600

__device__ __forceinline__ float sigf(float x) { return 1.f / (1.f + __expf(-x)); }

// ---------------- K1: FIR kernels + spread connectivity masks ----------------
__global__ __launch_bounds__(256) void k1_precomp(
    const float* __restrict__ Ce, const float* __restrict__ Ci,
    const float* __restrict__ Wsy_s, const float* __restrict__ Wsy_ns,
    const float* __restrict__ Del_s, const float* __restrict__ Del_ns,
    float* __restrict__ ws) {
  int p = blockIdx.x * 256 + threadIdx.x;
  if (p < 2400) {
    int k = p / 12, s = p - (p / 12) * 12;
    float o[4];
    for (int ch = 0; ch < 2; ++ch) {
      const float* W = ch ? Wsy_ns : Wsy_s;
      const float* D = ch ? Del_ns : Del_s;
      for (int c = 0; c < 2; ++c) {
        float ts = fmaxf((float)k - __expf(D[s * 2 + c]), 0.f);
        float v = 0.f;
        for (int b = 0; b < 3; ++b) {
          float tt = ts * __expf(-0.5f * (float)b);
          v += W[s * 6 + b * 2 + c] * tt * __expf(-tt);
        }
        o[ch * 2 + c] = v;
      }
    }
    float* H = ws + WS_H + (size_t)(k * 12 + s) * 4;
    H[0] = o[0]; H[1] = o[1]; H[2] = o[2]; H[3] = o[3];
  }
  int q = p - 2400;
  if (q >= 0 && q < 2500) {
    uint m = 0;
    if (q < 2000) {
      for (int s = 0; s < 12; ++s) m |= (Ce[s * 2000 + q] != 0.f ? (1u << s) : 0u);
    } else {
      int e = q - 2000;
      for (int s = 0; s < 12; ++s) m |= (Ci[s * 500 + e] != 0.f ? (1u << s) : 0u);
    }
    u64 sp = 0ull;
    for (int s = 0; s < 12; ++s) sp |= (u64)((m >> s) & 1u) << (5 * s);
    ((uint2*)(ws + WS_SPREAD))[q] = make_uint2((uint)sp, (uint)(sp >> 32));
  }
}

// ---------------- K2: IN = S @ C^T via spread-mask accumulation ----------------
// 2 rows per wave (10000 waves). Per element: cmp + cndmask*2 + add64 = 5 VALU.
// 5-bit fields (bit 5s per subunit); flush every 4 float4s (max 16 per field).
__global__ __launch_bounds__(256) void k2_project(
    const float* __restrict__ Se, const float* __restrict__ Si,
    float* __restrict__ ws) {
  __shared__ __align__(16) uint2 sp[2500];
  {
    const uint2* g = (const uint2*)(ws + WS_SPREAD);
    for (int p = threadIdx.x; p < 2500; p += 256) sp[p] = g[p];
  }
  __syncthreads();
  const int lane = threadIdx.x & 63;
  const int wv = blockIdx.x * 4 + (threadIdx.x >> 6);  // 10000 waves
  const uint4* SP4 = (const uint4*)sp;
  float* INb = ws + WS_IN;
  for (int r = 0; r < 2; ++r) {
    const int t = wv * 2 + r;
    uint eTot[12];
#pragma unroll
    for (int s = 0; s < 12; ++s) eTot[s] = 0u;
    u64 acc = 0ull;
    const float4* Sr = (const float4*)(Se + (size_t)t * 2000);
#pragma unroll
    for (int it = 0; it < 8; ++it) {
      int i4 = lane + it * 64;
      if (i4 < 500) {
        float4 sv = Sr[i4];
        uint4 a = SP4[2 * i4];
        uint4 b = SP4[2 * i4 + 1];
        u64 m0 = (u64)a.x | ((u64)a.y << 32);
        u64 m1 = (u64)a.z | ((u64)a.w << 32);
        u64 m2 = (u64)b.x | ((u64)b.y << 32);
        u64 m3 = (u64)b.z | ((u64)b.w << 32);
        acc += (sv.x != 0.f ? m0 : 0ull);
        acc += (sv.y != 0.f ? m1 : 0ull);
        acc += (sv.z != 0.f ? m2 : 0ull);
        acc += (sv.w != 0.f ? m3 : 0ull);
      }
      if (it == 3) {
#pragma unroll
        for (int s = 0; s < 12; ++s) eTot[s] += (uint)(acc >> (5 * s)) & 31u;
        acc = 0ull;
      }
    }
#pragma unroll
    for (int s = 0; s < 12; ++s) eTot[s] += (uint)(acc >> (5 * s)) & 31u;
    // ----- I channel (max 8 per field, no flush needed) -----
    u64 accI = 0ull;
    const float4* Sir = (const float4*)(Si + (size_t)t * 500);
#pragma unroll
    for (int it = 0; it < 2; ++it) {
      int i4 = lane + it * 64;
      if (i4 < 125) {
        float4 sv = Sir[i4];
        uint4 a = SP4[1000 + 2 * i4];
        uint4 b = SP4[1000 + 2 * i4 + 1];
        u64 m0 = (u64)a.x | ((u64)a.y << 32);
        u64 m1 = (u64)a.z | ((u64)a.w << 32);
        u64 m2 = (u64)b.x | ((u64)b.y << 32);
        u64 m3 = (u64)b.z | ((u64)b.w << 32);
        accI += (sv.x != 0.f ? m0 : 0ull);
        accI += (sv.y != 0.f ? m1 : 0ull);
        accI += (sv.z != 0.f ? m2 : 0ull);
        accI += (sv.w != 0.f ? m3 : 0ull);
      }
    }
    uint pk[12];
#pragma unroll
    for (int s = 0; s < 12; ++s)
      pk[s] = eTot[s] | (((uint)(accI >> (5 * s)) & 31u) << 16);
#pragma unroll
    for (int s = 0; s < 12; ++s) {
      uint v = pk[s];
      v += __shfl_xor(v, 32, 64);
      v += __shfl_xor(v, 16, 64);
      v += __shfl_xor(v, 8, 64);
      v += __shfl_xor(v, 4, 64);
      v += __shfl_xor(v, 2, 64);
      v += __shfl_xor(v, 1, 64);
      pk[s] = v;
    }
    if (lane == 0) {
      float4* o = (float4*)(INb + (size_t)t * 24);
      o[0] = make_float4((float)(pk[0] & 0xffffu), (float)(pk[1] & 0xffffu),
                         (float)(pk[2] & 0xffffu), (float)(pk[3] & 0xffffu));
      o[1] = make_float4((float)(pk[4] & 0xffffu), (float)(pk[5] & 0xffffu),
                         (float)(pk[6] & 0xffffu), (float)(pk[7] & 0xffffu));
      o[2] = make_float4((float)(pk[8] & 0xffffu), (float)(pk[9] & 0xffffu),
                         (float)(pk[10] & 0xffffu), (float)(pk[11] & 0xffffu));
      o[3] = make_float4((float)(pk[0] >> 16), (float)(pk[1] >> 16),
                         (float)(pk[2] >> 16), (float)(pk[3] >> 16));
      o[4] = make_float4((float)(pk[4] >> 16), (float)(pk[5] >> 16),
                         (float)(pk[6] >> 16), (float)(pk[7] >> 16));
      o[5] = make_float4((float)(pk[8] >> 16), (float)(pk[9] >> 16),
                         (float)(pk[10] >> 16), (float)(pk[11] >> 16));
    }
  }
}

// ---------------- K3: causal FIR, K=200, s-group split across blockIdx.y ----------------
// block = 64 t's x 3 subunits (both channels); 4 waves split the 200 taps.
__global__ __launch_bounds__(256) void k3_conv(float* __restrict__ ws) {
  __shared__ float tile[6 * 264];
  __shared__ float red[4 * 64 * 6];
  const int g = blockIdx.y;        // subunit group: s in [3g, 3g+3)
  const int t0 = blockIdx.x * 64;
  const float* INb = ws + WS_IN;
  for (int p = threadIdx.x; p < 263 * 6; p += 256) {
    int row = p / 6, c = p - row * 6;
    int ch = (c < 3) ? (3 * g + c) : (9 + 3 * g + c);  // e: 3g+c ; i: 12+3g+(c-3)
    int gt = t0 - 199 + row;
    tile[c * 264 + row] = (gt >= 0 && gt < TD) ? INb[(size_t)gt * 24 + ch] : 0.f;
  }
  __syncthreads();
  const int lane = threadIdx.x & 63;
  const int q = threadIdx.x >> 6;
  const float4* H4 = (const float4*)(ws + WS_H);
  float accs[3] = {0.f, 0.f, 0.f}, accn[3] = {0.f, 0.f, 0.f};
  for (int kk = 0; kk < 25; ++kk) {
    int k = q * 50 + kk * 2;      // taps k and k+1
    int rb = lane + 198 - k;      // LDS row of tap k+1 (tap k at rb+1)
#pragma unroll
    for (int s = 0; s < 3; ++s) {
      float ve0 = tile[s * 264 + rb];
      float ve1 = tile[s * 264 + rb + 1];
      float vi0 = tile[(3 + s) * 264 + rb];
      float vi1 = tile[(3 + s) * 264 + rb + 1];
      float4 h0 = H4[k * 12 + 3 * g + s];
      float4 h1 = H4[(k + 1) * 12 + 3 * g + s];
      accs[s] += h0.x * ve1 + h0.y * vi1 + h1.x * ve0 + h1.y * vi0;
      accn[s] += h0.z * ve1 + h0.w * vi1 + h1.z * ve0 + h1.w * vi0;
    }
  }
  float* mr = red + (q * 64 + lane) * 6;
#pragma unroll
  for (int s = 0; s < 3; ++s) { mr[s] = accs[s]; mr[3 + s] = accn[s]; }
  __syncthreads();
  for (int p = threadIdx.x; p < 64 * 6; p += 256) {
    int row = p / 6, c = p - row * 6;
    if (t0 + row < TD) {
      float sum = red[p] + red[384 + p] + red[768 + p] + red[1152 + p];
      int ch = (c < 3) ? (3 * g + c) : (9 + 3 * g + c);
      ws[WS_SYN + (size_t)(t0 + row) * 24 + ch] = sum;
    }
  }
}

// ---------------- K45: one thread per t. C_den strictly lower-tri => nilpotent
// => 12-step influence horizon; 13-step warm-up makes A[t-1] and A[t] exact.
// s-chain is non-recurrent given A[t-1] (B[t-1][0] is closed-form). ----------------
__global__ void k45_out(
    const float* __restrict__ Cden, const float* __restrict__ Ws_sub,
    const float* __restrict__ Wns_sub, const float* __restrict__ Th_s,
    const float* __restrict__ Th_ns, const float* __restrict__ ws,
    float* __restrict__ out) {
  __shared__ float lout[64 * 35];
  const int t = blockIdx.x * 64 + threadIdx.x;
  float v[35];
#pragma unroll
  for (int m = 0; m < 35; ++m) v[m] = 0.f;
  if (t < TD) {
    const float* SYN = ws + WS_SYN;
    float dns[12][12];
#pragma unroll
    for (int i = 1; i < 12; ++i)
#pragma unroll
      for (int j = 0; j < i; ++j) dns[i][j] = Cden[i * 12 + j] * Wns_sub[j];
    float th[12];
#pragma unroll
    for (int i = 0; i < 12; ++i) th[i] = Th_ns[i];
    float ap[12], an[12];
#pragma unroll
    for (int i = 0; i < 12; ++i) { ap[i] = 0.f; an[i] = 0.f; }
    int start = t - 12; if (start < 0) start = 0;
    for (int tau = start; tau <= t; ++tau) {
      const float4* sr = (const float4*)(SYN + (size_t)tau * 24 + 12);
      float4 s0 = sr[0], s1 = sr[1], s2 = sr[2];
      float sn[12] = {s0.x, s0.y, s0.z, s0.w, s1.x, s1.y, s1.z, s1.w,
                      s2.x, s2.y, s2.z, s2.w};
#pragma unroll
      for (int i = 0; i < 12; ++i) {
        float x = sn[i] + th[i];
#pragma unroll
        for (int j = 0; j < i; ++j) x += dns[i][j] * ap[j];
        an[i] = sigf(x);
      }
      if (tau < t) {
#pragma unroll
        for (int i = 0; i < 12; ++i) ap[i] = an[i];
      }
    }
    // an = A[t], ap = A[t-1] (zeros if t==0)
    float sns[12];
    {
      const float4* sr = (const float4*)(SYN + (size_t)t * 24);
      float4 s0 = sr[0], s1 = sr[1], s2 = sr[2];
      sns[0] = s0.x; sns[1] = s0.y; sns[2] = s0.z; sns[3] = s0.w;
      sns[4] = s1.x; sns[5] = s1.y; sns[6] = s1.z; sns[7] = s1.w;
      sns[8] = s2.x; sns[9] = s2.y; sns[10] = s2.z; sns[11] = s2.w;
    }
    float carry[12];
    carry[0] = (t > 0) ? Ws_sub[0] * sigf(SYN[(size_t)(t - 1) * 24] + Th_s[0]) : 0.f;
#pragma unroll
    for (int j = 1; j < 12; ++j) carry[j] = Ws_sub[j] * ap[j];
    float B[12];
#pragma unroll
    for (int i = 0; i < 12; ++i) {
      float x = sns[i] + Th_s[i];
#pragma unroll
      for (int j = 0; j < i; ++j) x += Cden[i * 12 + j] * carry[j];
      B[i] = sigf(x);
    }
    v[0] = B[0] * Ws_sub[0];
#pragma unroll
    for (int i = 1; i < 12; ++i) v[i] = an[i] * Ws_sub[i];
#pragma unroll
    for (int i = 0; i < 12; ++i) v[12 + i] = an[i] * Wns_sub[i];
#pragma unroll
    for (int i = 1; i < 12; ++i) v[23 + i] = B[i];
  }
#pragma unroll
  for (int m = 0; m < 35; ++m) lout[threadIdx.x * 35 + m] = v[m];
  __syncthreads();
  const int t0 = blockIdx.x * 64;
  int nrow = TD - t0; if (nrow > 64) nrow = 64;
  const int valid = nrow * 35;
  for (int p = threadIdx.x; p < valid; p += 64) out[(size_t)t0 * 35 + p] = lout[p];
}

extern "C" void kernel_launch(void* const* d_in, const int* in_sizes, int n_in,
                              void* d_out, int out_size, void* d_ws, size_t ws_size,
                              hipStream_t stream) {
  const float* Se = (const float*)d_in[0];
  const float* Si = (const float*)d_in[1];
  const float* Ce = (const float*)d_in[2];
  const float* Ci = (const float*)d_in[3];
  const float* Cden = (const float*)d_in[4];
  const float* Wsy_s = (const float*)d_in[5];
  const float* Wsy_ns = (const float*)d_in[6];
  const float* Del_s = (const float*)d_in[7];
  const float* Del_ns = (const float*)d_in[8];
  const float* Th_s = (const float*)d_in[9];
  const float* Th_ns = (const float*)d_in[10];
  const float* Ws_sub = (const float*)d_in[11];
  const float* Wns_sub = (const float*)d_in[12];
  // d_in[13..16] (hist/prop weights) multiply an identically-zero history buffer.
  float* ws = (float*)d_ws;
  float* out = (float*)d_out;

  k1_precomp<<<20, 256, 0, stream>>>(Ce, Ci, Wsy_s, Wsy_ns, Del_s, Del_ns, ws);
  k2_project<<<2500, 256, 0, stream>>>(Se, Si, ws);
  dim3 g3(313, 4);
  k3_conv<<<g3, 256, 0, stream>>>(ws);
  k45_out<<<313, 64, 0, stream>>>(Cden, Ws_sub, Wns_sub, Th_s, Th_ns, ws, out);
}

// Round 3
// 326.998 us; speedup vs baseline: 1.1145x; 1.0184x over previous
//
#include <hip/hip_runtime.h>

typedef unsigned int uint;
typedef unsigned long long u64;

#define TD 20000
// ws layout in float units:
//  H:      [200][12][4]  = 9600 floats  (FIR taps: {e_s, i_s, e_ns, i_ns} per (k,s))
//  SPREAD: 2500 uint2    (5-bit-field spread masks: bit s of connectivity -> bit 5s)
//          entries 0..1999 = E neurons, 2000..2499 = I neurons
//  IN:     [20000][24]   (e counts in 0..11, i counts in 12..23)
//  SYN:    [20000][24]   (syn_s in 0..11, syn_ns in 12..23)
#define WS_H      0
#define WS_SPREAD 9600
#define WS_IN     14600
#define WS_SYN    494600

__device__ __forceinline__ float sigf(float x) { return 1.f / (1.f + __expf(-x)); }

// ---------------- K1: FIR kernels + spread connectivity masks ----------------
__global__ __launch_bounds__(256) void k1_precomp(
    const float* __restrict__ Ce, const float* __restrict__ Ci,
    const float* __restrict__ Wsy_s, const float* __restrict__ Wsy_ns,
    const float* __restrict__ Del_s, const float* __restrict__ Del_ns,
    float* __restrict__ ws) {
  int p = blockIdx.x * 256 + threadIdx.x;
  if (p < 2400) {
    int k = p / 12, s = p - (p / 12) * 12;
    float o[4];
    for (int ch = 0; ch < 2; ++ch) {
      const float* W = ch ? Wsy_ns : Wsy_s;
      const float* D = ch ? Del_ns : Del_s;
      for (int c = 0; c < 2; ++c) {
        float ts = fmaxf((float)k - __expf(D[s * 2 + c]), 0.f);
        float v = 0.f;
        for (int b = 0; b < 3; ++b) {
          float tt = ts * __expf(-0.5f * (float)b);
          v += W[s * 6 + b * 2 + c] * tt * __expf(-tt);
        }
        o[ch * 2 + c] = v;
      }
    }
    float* H = ws + WS_H + (size_t)(k * 12 + s) * 4;
    H[0] = o[0]; H[1] = o[1]; H[2] = o[2]; H[3] = o[3];
  }
  int q = p - 2400;
  if (q >= 0 && q < 2500) {
    uint m = 0;
    if (q < 2000) {
      for (int s = 0; s < 12; ++s) m |= (Ce[s * 2000 + q] != 0.f ? (1u << s) : 0u);
    } else {
      int e = q - 2000;
      for (int s = 0; s < 12; ++s) m |= (Ci[s * 500 + e] != 0.f ? (1u << s) : 0u);
    }
    u64 sp = 0ull;
    for (int s = 0; s < 12; ++s) sp |= (u64)((m >> s) & 1u) << (5 * s);
    ((uint2*)(ws + WS_SPREAD))[q] = make_uint2((uint)sp, (uint)(sp >> 32));
  }
}

// ---------------- K2: IN = S @ C^T via spread-mask accumulation ----------------
// 1 row per wave (20000 waves -> deep oversubscription for latency hiding).
// Per element: cmp + cndmask*2 + add64 = 5 VALU. 5-bit fields (bit 5s per
// subunit); flush E accumulator at half-way (max 16 < 31 per field).
__global__ __launch_bounds__(256) void k2_project(
    const float* __restrict__ Se, const float* __restrict__ Si,
    float* __restrict__ ws) {
  __shared__ __align__(16) uint2 sp[2500];
  {
    const uint2* g = (const uint2*)(ws + WS_SPREAD);
    for (int p = threadIdx.x; p < 2500; p += 256) sp[p] = g[p];
  }
  __syncthreads();
  const int lane = threadIdx.x & 63;
  const int t = blockIdx.x * 4 + (threadIdx.x >> 6);  // one time-row per wave
  const uint4* SP4 = (const uint4*)sp;
  float* INb = ws + WS_IN;

  uint eTot[12];
#pragma unroll
  for (int s = 0; s < 12; ++s) eTot[s] = 0u;
  u64 acc = 0ull;
  const float4* Sr = (const float4*)(Se + (size_t)t * 2000);
#pragma unroll
  for (int it = 0; it < 8; ++it) {
    int i4 = lane + it * 64;
    if (i4 < 500) {
      float4 sv = Sr[i4];
      uint4 a = SP4[2 * i4];
      uint4 b = SP4[2 * i4 + 1];
      u64 m0 = (u64)a.x | ((u64)a.y << 32);
      u64 m1 = (u64)a.z | ((u64)a.w << 32);
      u64 m2 = (u64)b.x | ((u64)b.y << 32);
      u64 m3 = (u64)b.z | ((u64)b.w << 32);
      acc += (sv.x != 0.f ? m0 : 0ull);
      acc += (sv.y != 0.f ? m1 : 0ull);
      acc += (sv.z != 0.f ? m2 : 0ull);
      acc += (sv.w != 0.f ? m3 : 0ull);
    }
    if (it == 3) {
#pragma unroll
      for (int s = 0; s < 12; ++s) eTot[s] += (uint)(acc >> (5 * s)) & 31u;
      acc = 0ull;
    }
  }
#pragma unroll
  for (int s = 0; s < 12; ++s) eTot[s] += (uint)(acc >> (5 * s)) & 31u;
  // ----- I channel (max 8 per field, no flush needed) -----
  u64 accI = 0ull;
  const float4* Sir = (const float4*)(Si + (size_t)t * 500);
#pragma unroll
  for (int it = 0; it < 2; ++it) {
    int i4 = lane + it * 64;
    if (i4 < 125) {
      float4 sv = Sir[i4];
      uint4 a = SP4[1000 + 2 * i4];
      uint4 b = SP4[1000 + 2 * i4 + 1];
      u64 m0 = (u64)a.x | ((u64)a.y << 32);
      u64 m1 = (u64)a.z | ((u64)a.w << 32);
      u64 m2 = (u64)b.x | ((u64)b.y << 32);
      u64 m3 = (u64)b.z | ((u64)b.w << 32);
      accI += (sv.x != 0.f ? m0 : 0ull);
      accI += (sv.y != 0.f ? m1 : 0ull);
      accI += (sv.z != 0.f ? m2 : 0ull);
      accI += (sv.w != 0.f ? m3 : 0ull);
    }
  }
  uint pk[12];
#pragma unroll
  for (int s = 0; s < 12; ++s)
    pk[s] = eTot[s] | (((uint)(accI >> (5 * s)) & 31u) << 16);
#pragma unroll
  for (int s = 0; s < 12; ++s) {
    uint v = pk[s];
    v += __shfl_xor(v, 32, 64);
    v += __shfl_xor(v, 16, 64);
    v += __shfl_xor(v, 8, 64);
    v += __shfl_xor(v, 4, 64);
    v += __shfl_xor(v, 2, 64);
    v += __shfl_xor(v, 1, 64);
    pk[s] = v;
  }
  if (lane == 0) {
    float4* o = (float4*)(INb + (size_t)t * 24);
    o[0] = make_float4((float)(pk[0] & 0xffffu), (float)(pk[1] & 0xffffu),
                       (float)(pk[2] & 0xffffu), (float)(pk[3] & 0xffffu));
    o[1] = make_float4((float)(pk[4] & 0xffffu), (float)(pk[5] & 0xffffu),
                       (float)(pk[6] & 0xffffu), (float)(pk[7] & 0xffffu));
    o[2] = make_float4((float)(pk[8] & 0xffffu), (float)(pk[9] & 0xffffu),
                       (float)(pk[10] & 0xffffu), (float)(pk[11] & 0xffffu));
    o[3] = make_float4((float)(pk[0] >> 16), (float)(pk[1] >> 16),
                       (float)(pk[2] >> 16), (float)(pk[3] >> 16));
    o[4] = make_float4((float)(pk[4] >> 16), (float)(pk[5] >> 16),
                       (float)(pk[6] >> 16), (float)(pk[7] >> 16));
    o[5] = make_float4((float)(pk[8] >> 16), (float)(pk[9] >> 16),
                       (float)(pk[10] >> 16), (float)(pk[11] >> 16));
  }
}

// ---------------- K3: causal FIR, K=200, s-group split across blockIdx.y ----------------
// block = 64 t's x 3 subunits (both channels); 4 waves split the 200 taps.
// red[] row stride 7 (gcd(7,32)=1 -> conflict-free; stride 6 was 4-way aliased).
__global__ __launch_bounds__(256) void k3_conv(float* __restrict__ ws) {
  __shared__ float tile[6 * 264];
  __shared__ float red[4 * 64 * 7];
  const int g = blockIdx.y;        // subunit group: s in [3g, 3g+3)
  const int t0 = blockIdx.x * 64;
  const float* INb = ws + WS_IN;
  for (int p = threadIdx.x; p < 263 * 6; p += 256) {
    int row = p / 6, c = p - row * 6;
    int ch = (c < 3) ? (3 * g + c) : (9 + 3 * g + c);  // e: 3g+c ; i: 12+3g+(c-3)
    int gt = t0 - 199 + row;
    tile[c * 264 + row] = (gt >= 0 && gt < TD) ? INb[(size_t)gt * 24 + ch] : 0.f;
  }
  __syncthreads();
  const int lane = threadIdx.x & 63;
  const int q = threadIdx.x >> 6;
  const float4* H4 = (const float4*)(ws + WS_H);
  float accs[3] = {0.f, 0.f, 0.f}, accn[3] = {0.f, 0.f, 0.f};
  for (int kk = 0; kk < 25; ++kk) {
    int k = q * 50 + kk * 2;      // taps k and k+1
    int rb = lane + 198 - k;      // LDS row of tap k+1 (tap k at rb+1)
#pragma unroll
    for (int s = 0; s < 3; ++s) {
      float ve0 = tile[s * 264 + rb];
      float ve1 = tile[s * 264 + rb + 1];
      float vi0 = tile[(3 + s) * 264 + rb];
      float vi1 = tile[(3 + s) * 264 + rb + 1];
      float4 h0 = H4[k * 12 + 3 * g + s];
      float4 h1 = H4[(k + 1) * 12 + 3 * g + s];
      accs[s] += h0.x * ve1 + h0.y * vi1 + h1.x * ve0 + h1.y * vi0;
      accn[s] += h0.z * ve1 + h0.w * vi1 + h1.z * ve0 + h1.w * vi0;
    }
  }
  float* mr = red + (q * 64 + lane) * 7;
#pragma unroll
  for (int s = 0; s < 3; ++s) { mr[s] = accs[s]; mr[3 + s] = accn[s]; }
  __syncthreads();
  for (int p = threadIdx.x; p < 64 * 6; p += 256) {
    int row = p / 6, c = p - row * 6;
    if (t0 + row < TD) {
      float sum = red[row * 7 + c] + red[(64 + row) * 7 + c] +
                  red[(128 + row) * 7 + c] + red[(192 + row) * 7 + c];
      int ch = (c < 3) ? (3 * g + c) : (9 + 3 * g + c);
      ws[WS_SYN + (size_t)(t0 + row) * 24 + ch] = sum;
    }
  }
}

// ---------------- K45: one thread per t. C_den strictly lower-tri => nilpotent
// => bounded influence horizon; 13-step warm-up makes A[t-1] and A[t] exact.
// s-chain is non-recurrent given A[t-1] (B[t-1][0] is closed-form). ----------------
__global__ void k45_out(
    const float* __restrict__ Cden, const float* __restrict__ Ws_sub,
    const float* __restrict__ Wns_sub, const float* __restrict__ Th_s,
    const float* __restrict__ Th_ns, const float* __restrict__ ws,
    float* __restrict__ out) {
  __shared__ float lout[64 * 35];
  const int t = blockIdx.x * 64 + threadIdx.x;
  float v[35];
#pragma unroll
  for (int m = 0; m < 35; ++m) v[m] = 0.f;
  if (t < TD) {
    const float* SYN = ws + WS_SYN;
    float dns[12][12];
#pragma unroll
    for (int i = 1; i < 12; ++i)
#pragma unroll
      for (int j = 0; j < i; ++j) dns[i][j] = Cden[i * 12 + j] * Wns_sub[j];
    float th[12];
#pragma unroll
    for (int i = 0; i < 12; ++i) th[i] = Th_ns[i];
    float ap[12], an[12];
#pragma unroll
    for (int i = 0; i < 12; ++i) { ap[i] = 0.f; an[i] = 0.f; }
    int start = t - 12; if (start < 0) start = 0;
    for (int tau = start; tau <= t; ++tau) {
      const float4* sr = (const float4*)(SYN + (size_t)tau * 24 + 12);
      float4 s0 = sr[0], s1 = sr[1], s2 = sr[2];
      float sn[12] = {s0.x, s0.y, s0.z, s0.w, s1.x, s1.y, s1.z, s1.w,
                      s2.x, s2.y, s2.z, s2.w};
#pragma unroll
      for (int i = 0; i < 12; ++i) {
        float x = sn[i] + th[i];
#pragma unroll
        for (int j = 0; j < i; ++j) x += dns[i][j] * ap[j];
        an[i] = sigf(x);
      }
      if (tau < t) {
#pragma unroll
        for (int i = 0; i < 12; ++i) ap[i] = an[i];
      }
    }
    // an = A[t], ap = A[t-1] (zeros if t==0)
    float sns[12];
    {
      const float4* sr = (const float4*)(SYN + (size_t)t * 24);
      float4 s0 = sr[0], s1 = sr[1], s2 = sr[2];
      sns[0] = s0.x; sns[1] = s0.y; sns[2] = s0.z; sns[3] = s0.w;
      sns[4] = s1.x; sns[5] = s1.y; sns[6] = s1.z; sns[7] = s1.w;
      sns[8] = s2.x; sns[9] = s2.y; sns[10] = s2.z; sns[11] = s2.w;
    }
    float carry[12];
    carry[0] = (t > 0) ? Ws_sub[0] * sigf(SYN[(size_t)(t - 1) * 24] + Th_s[0]) : 0.f;
#pragma unroll
    for (int j = 1; j < 12; ++j) carry[j] = Ws_sub[j] * ap[j];
    float B[12];
#pragma unroll
    for (int i = 0; i < 12; ++i) {
      float x = sns[i] + Th_s[i];
#pragma unroll
      for (int j = 0; j < i; ++j) x += Cden[i * 12 + j] * carry[j];
      B[i] = sigf(x);
    }
    v[0] = B[0] * Ws_sub[0];
#pragma unroll
    for (int i = 1; i < 12; ++i) v[i] = an[i] * Ws_sub[i];
#pragma unroll
    for (int i = 0; i < 12; ++i) v[12 + i] = an[i] * Wns_sub[i];
#pragma unroll
    for (int i = 1; i < 12; ++i) v[23 + i] = B[i];
  }
#pragma unroll
  for (int m = 0; m < 35; ++m) lout[threadIdx.x * 35 + m] = v[m];
  __syncthreads();
  const int t0 = blockIdx.x * 64;
  int nrow = TD - t0; if (nrow > 64) nrow = 64;
  const int valid = nrow * 35;
  for (int p = threadIdx.x; p < valid; p += 64) out[(size_t)t0 * 35 + p] = lout[p];
}

extern "C" void kernel_launch(void* const* d_in, const int* in_sizes, int n_in,
                              void* d_out, int out_size, void* d_ws, size_t ws_size,
                              hipStream_t stream) {
  const float* Se = (const float*)d_in[0];
  const float* Si = (const float*)d_in[1];
  const float* Ce = (const float*)d_in[2];
  const float* Ci = (const float*)d_in[3];
  const float* Cden = (const float*)d_in[4];
  const float* Wsy_s = (const float*)d_in[5];
  const float* Wsy_ns = (const float*)d_in[6];
  const float* Del_s = (const float*)d_in[7];
  const float* Del_ns = (const float*)d_in[8];
  const float* Th_s = (const float*)d_in[9];
  const float* Th_ns = (const float*)d_in[10];
  const float* Ws_sub = (const float*)d_in[11];
  const float* Wns_sub = (const float*)d_in[12];
  // d_in[13..16] (hist/prop weights) multiply an identically-zero history buffer.
  float* ws = (float*)d_ws;
  float* out = (float*)d_out;

  k1_precomp<<<20, 256, 0, stream>>>(Ce, Ci, Wsy_s, Wsy_ns, Del_s, Del_ns, ws);
  k2_project<<<5000, 256, 0, stream>>>(Se, Si, ws);
  dim3 g3(313, 4);
  k3_conv<<<g3, 256, 0, stream>>>(ws);
  k45_out<<<313, 64, 0, stream>>>(Cden, Ws_sub, Wns_sub, Th_s, Th_ns, ws, out);
}